// Round 17
// baseline (157.083 us; speedup 1.0000x reference)
//
#include <hip/hip_runtime.h>
#include <stdint.h>

// ---------------------------------------------------------------------------
// CausalSelfAttention (T=4096, DIM=1024, 16 heads x 64) on gfx950, bf16 MFMA.
// Pipeline: prep(rope tables + casts) | GEMM1 qkv (XCD-swizzled) |
//           fuse(vmix,rms,rope -> BLOCKED Q/K + BLOCKED V^T) | flash attn
//           (swapped 32x32, split-KV x4, blocked coalesced loads, scale-free
//           softmax via raw v_exp_f32, shfl exchange, ones-MFMA rowsum,
//           interleaved long/short q-tile order) | GEMM2 -> fp32
//
// r16 lesson: pair-balancing halved the grid to 1024 -> only 4 blocks/CU
// resident (50% occupancy cap) and a mid-kernel merge barrier -> SLOWER.
// Keep 2048 blocks (8/CU); fight the drain tail with an interleaved
// long/short qb mapping instead (launch stream alternates lengths).
// Scale-free softmax: O = sum(P V)/sum(P) invariant to uniform P-scale;
// P' = exp2(s) raw v_exp_f32 (s <= 11.2 by RMS-norm bound; no denormals).
// r14 lesson: no reg-prefetch rotation (scratch spills). r10 lesson: never
// raise min-waves launch bound. BANNED: v_permlane32_swap (r8/r12).
// ---------------------------------------------------------------------------

typedef __attribute__((ext_vector_type(8))) __bf16 bf16x8;
typedef __attribute__((ext_vector_type(8))) unsigned short u16x8;
typedef __attribute__((ext_vector_type(4))) float f32x4;
typedef __attribute__((ext_vector_type(16))) float f32x16;

union U8 { u16x8 s; bf16x8 b; };
union PF { unsigned int u[4]; u16x8 s; bf16x8 b; };

__device__ __forceinline__ float bf2f(unsigned short u) {
  union { unsigned int i; float f; } c; c.i = ((unsigned int)u) << 16; return c.f;
}
__device__ __forceinline__ unsigned short f2bf(float f) {
  union { __bf16 h; unsigned short u; } c; c.h = (__bf16)f; return c.u;
}
__device__ __forceinline__ unsigned int pk2(float lo, float hi) {
  return (unsigned int)f2bf(lo) | ((unsigned int)f2bf(hi) << 16);
}
__device__ __forceinline__ float fexp2(float x) {  // raw HW exp2, 1 inst
  float r;
  asm("v_exp_f32 %0, %1" : "=v"(r) : "v"(x));
  return r;
}

// async global->LDS, 16B per lane (GEMM staging only)
#define GLOAD16(gp, lp)                                                         \
  __builtin_amdgcn_global_load_lds(                                             \
      (const __attribute__((address_space(1))) void*)(gp),                      \
      (__attribute__((address_space(3))) void*)(lp), 16, 0, 0)

#define MFMA16(a, b, c) __builtin_amdgcn_mfma_f32_16x16x32_bf16((a), (b), (c), 0, 0, 0)
#define MFMA32(a, b, c) __builtin_amdgcn_mfma_f32_32x32x16_bf16((a), (b), (c), 0, 0, 0)

constexpr float ATTN_SCALE = 0.12f;
constexpr float LOG2E = 1.44269504088896340736f;
constexpr float QSCALE = ATTN_SCALE * LOG2E;  // folded into Q at fuse stage

// --------------------------- prep: rope tables + f32->bf16 casts ------------
__global__ __launch_bounds__(256) void prep(
    const float* __restrict__ x, const float* __restrict__ qw,
    const float* __restrict__ pw, float* __restrict__ ct, float* __restrict__ st,
    unsigned short* __restrict__ wsbf) {
  const int b = (int)blockIdx.x;
  if (b < 512) {
    const int i = b * 256 + threadIdx.x;
    const int tt = i >> 5, k = i & 31;
    float cv = 1.0f, sv = 0.0f;
    if (k < 16) {
      const float af = powf(1.0f / 1024.0f, (float)k * (1.0f / 15.0f));
      const float th = (float)tt * af;
      cv = cosf(th);
      sv = sinf(th);
    }
    ct[i] = cv; st[i] = sv;
    return;
  }
  const int i8 = (b - 512) * 256 + threadIdx.x;
  const float* src;
  if (i8 < 524288) src = x + (size_t)i8 * 8;
  else if (i8 < 917504) src = qw + (size_t)(i8 - 524288) * 8;
  else src = pw + (size_t)(i8 - 917504) * 8;
  const float4 a = ((const float4*)src)[0];
  const float4 c = ((const float4*)src)[1];
  u16x8 o;
  o[0] = f2bf(a.x); o[1] = f2bf(a.y); o[2] = f2bf(a.z); o[3] = f2bf(a.w);
  o[4] = f2bf(c.x); o[5] = f2bf(c.y); o[6] = f2bf(c.z); o[7] = f2bf(c.w);
  ((u16x8*)wsbf)[i8] = o;
}

// --------------------------- GEMM: C[M][N] = A[M][K] * B[N][K]^T -----------
template <int OUT_BF16>
__global__ __launch_bounds__(256) void gemm_bt(
    const unsigned short* __restrict__ A, const unsigned short* __restrict__ B,
    void* __restrict__ Cout, int M, int N, int K) {
  __shared__ unsigned short lA[128 * 32];
  __shared__ unsigned short lB[128 * 32];
  const int nbn = N >> 7;
  const int cpx = (int)gridDim.x >> 3;
  const int bid = (int)blockIdx.x;
  const int sb = (bid & 7) * cpx + (bid >> 3);  // same-XCD blocks contiguous
  const int bm = sb / nbn, bn = sb % nbn;
  const int t = threadIdx.x;
  const int w = t >> 6, l = t & 63;
  const int g = l >> 4, c = l & 15;
  const int wr = (w >> 1) * 64, wc = (w & 1) * 64;

  const int srow = t >> 2;
  const int scol = ((t & 3) << 4) ^ ((srow & 3) << 4);  // byte col, XOR swizzle
  const char* ga = (const char*)(A + (size_t)(bm * 128 + srow) * K) + scol;
  const char* gb = (const char*)(B + (size_t)(bn * 128 + srow) * K) + scol;
  const size_t rowK2 = (size_t)64 * K * 2;
  char* la_dst = (char*)lA + t * 16;
  char* lb_dst = (char*)lB + t * 16;

  f32x4 acc[4][4] = {};

  for (int kt = 0; kt < K; kt += 32) {
    const char* gak = ga + (size_t)kt * 2;
    const char* gbk = gb + (size_t)kt * 2;
    GLOAD16(gak, la_dst);
    GLOAD16(gak + rowK2, la_dst + 4096);
    GLOAD16(gbk, lb_dst);
    GLOAD16(gbk + rowK2, lb_dst + 4096);
    __syncthreads();
    U8 af[4], bfr[4];
#pragma unroll
    for (int mi = 0; mi < 4; ++mi) {
      const int row = wr + 16 * mi + c;
      af[mi].s = *(const u16x8*)((const char*)lA + row * 64 + ((16 * g) ^ ((row & 3) << 4)));
    }
#pragma unroll
    for (int ni = 0; ni < 4; ++ni) {
      const int row = wc + 16 * ni + c;
      bfr[ni].s = *(const u16x8*)((const char*)lB + row * 64 + ((16 * g) ^ ((row & 3) << 4)));
    }
#pragma unroll
    for (int mi = 0; mi < 4; ++mi)
#pragma unroll
      for (int ni = 0; ni < 4; ++ni)
        acc[mi][ni] = MFMA16(af[mi].b, bfr[ni].b, acc[mi][ni]);
    __syncthreads();
  }
#pragma unroll
  for (int mi = 0; mi < 4; ++mi) {
#pragma unroll
    for (int ni = 0; ni < 4; ++ni) {
#pragma unroll
      for (int r = 0; r < 4; ++r) {
        const int row = bm * 128 + wr + 16 * mi + 4 * g + r;
        const int col = bn * 128 + wc + 16 * ni + c;
        const float v = acc[mi][ni][r];
        if (OUT_BF16)
          ((unsigned short*)Cout)[(size_t)row * N + col] = f2bf(v);
        else
          ((float*)Cout)[(size_t)row * N + col] = v;
      }
    }
  }
}

// --------------------------- fuse: vmix + rmsnorm + rope -> blocked --------
__device__ __forceinline__ void load64f(const unsigned short* p, float* x) {
#pragma unroll
  for (int j = 0; j < 8; ++j) {
    const u16x8 v = *(const u16x8*)(p + 8 * j);
#pragma unroll
    for (int e = 0; e < 8; ++e) x[8 * j + e] = bf2f(v[e]);
  }
}

__device__ __forceinline__ void rmsrope_store_blk(const float* x, const float* ct,
                                                  const float* st, unsigned short* outp,
                                                  float pscale) {
  float ms = 0.f;
#pragma unroll
  for (int j = 0; j < 64; ++j) ms += x[j] * x[j];
  const float sc = rsqrtf(ms * (1.0f / 64.0f) + 1.1920928955078125e-7f) * pscale;
  float y[64];
#pragma unroll
  for (int j = 0; j < 32; ++j) {
    const float cc = ct[j], ss = st[j];
    const float a = x[j] * sc, b = x[j + 32] * sc;
    y[j] = a * cc + b * ss;
    y[j + 32] = b * cc - a * ss;
  }
#pragma unroll
  for (int j = 0; j < 8; ++j) {
    u16x8 o;
#pragma unroll
    for (int e = 0; e < 8; ++e) o[e] = f2bf(y[8 * j + e]);
    *(u16x8*)(outp + 256 * j) = o;
  }
}

__global__ __launch_bounds__(256) void fuse_qkv(
    const unsigned short* __restrict__ qkv,  // [4096][3072] bf16
    const float* __restrict__ ve,            // [4096][1024]
    const float* __restrict__ lam,           // [2]
    const float* __restrict__ ct, const float* __restrict__ st,  // [4096][32]
    unsigned short* __restrict__ Qb,  // blocked [16][128 tiles][2048]
    unsigned short* __restrict__ Kb,  // blocked
    unsigned short* __restrict__ Vb)  // blocked V^T
{
  __shared__ unsigned short vtile[8][32][65];  // [group][kv][d], +1 pad
  const int b = (int)blockIdx.x;  // 256 blocks
  const int h = b & 15, tg = b >> 4;
  const int t = threadIdx.x;
  const int g = t >> 5, lq = t & 31;
  const int ti = tg * 8 + g;       // 32-row tile 0..127
  const int tt = ti * 32 + lq;

  const unsigned short* base = qkv + (size_t)tt * 3072 + h * 64;
  const float* ctp = ct + tt * 32;
  const float* stp = st + tt * 32;
  const size_t blk = (size_t)h * 262144 + (size_t)ti * 2048 + lq * 8;

  float x[64];
  load64f(base, x);
  rmsrope_store_blk(x, ctp, stp, Qb + blk, QSCALE);
  load64f(base + 1024, x);
  rmsrope_store_blk(x, ctp, stp, Kb + blk, 1.0f);

  // v mix -> LDS transpose tile
  const float l0 = lam[0], l1 = lam[1];
  const float* vp = ve + (size_t)tt * 1024 + h * 64;
  load64f(base + 2048, x);
#pragma unroll
  for (int j = 0; j < 64; ++j) vtile[g][lq][j] = f2bf(l0 * x[j] + l1 * vp[j]);
  __syncthreads();

  unsigned short* vo = Vb + (size_t)h * 262144 + (size_t)ti * 2048 + lq * 8;
#pragma unroll
  for (int r = 0; r < 4; ++r) {
    const int d = lq + 32 * (r & 1);
#pragma unroll
    for (int hi = 0; hi < 2; ++hi) {
      u16x8 o;
#pragma unroll
      for (int j = 0; j < 8; ++j) o[j] = vtile[g][16 * (r >> 1) + 8 * hi + j][d];
      *(u16x8*)(vo + r * 512 + hi * 256) = o;
    }
  }
}

// --------------------------- flash attention -------------------------------
// 2048 blocks (8/CU resident): block = (head, q-tile). Interleaved length
// order: u = b>>4, qb = odd(u) ? u/2 : 127-u/2 -> launch stream alternates
// long/short tiles (length-diverse residency, mid-length drain tail).
// 4 waves; split-KV: wave w owns kv-tiles ti = w, w+4, ...; private
// (osum, O^T), merged by plain sum. Loads issued-and-consumed in-iteration
// (r13 proven). Scale-free softmax (raw v_exp_f32). shfl_xor exchange.
// Row-sum on MFMA pipe. bf16 merge, 16.9KB LDS, launch_bounds(256,4).
__global__ __launch_bounds__(256, 4) void attn_fa(
    const unsigned short* __restrict__ Qb,  // blocked (scaled)
    const unsigned short* __restrict__ Kb,  // blocked
    const unsigned short* __restrict__ Vb,  // blocked V^T
    unsigned short* __restrict__ Y)         // [4096][1024]
{
  __shared__ unsigned short oLb[4][64][32];  // per-wave partial O^T (bf16)
  __shared__ float sumL[4][32];              // per-wave row sums

  const int b = (int)blockIdx.x;
  const int h = 2 * (b & 7) + ((b >> 3) & 1);  // same-h -> same XCD (b%8)
  const int u = b >> 4;                        // 0..127
  const int qb = (u & 1) ? (u >> 1) : 127 - (u >> 1);  // interleave long/short
  const int q0 = qb * 32;
  const int t = threadIdx.x;
  const int w = t >> 6, l = t & 63;
  const int lq = l & 31;    // this lane's q row
  const int hi = l >> 5;    // k/kv half selector

  const unsigned short* kh = Kb + (size_t)h * 262144 + l * 8;
  const unsigned short* vh = Vb + (size_t)h * 262144 + l * 8;

  // Q fragments: blocked tile qb
  U8 qf[4];
  {
    const unsigned short* qp = Qb + (size_t)h * 262144 + qb * 2048 + l * 8;
#pragma unroll
    for (int dd = 0; dd < 4; ++dd) qf[dd].s = *(const u16x8*)(qp + dd * 512);
  }

  U8 onesf;
#pragma unroll
  for (int e = 0; e < 8; ++e) onesf.s[e] = 0x3F80;  // bf16 1.0

  f32x16 o0 = {}, o1 = {};   // O^T: d rows 0-31 / 32-63, col q = lq
  f32x16 osum = {};          // row-sum accum on MFMA pipe (read [0])

  for (int ti = w; ti <= qb; ti += 4) {
    const unsigned short* kp = kh + ti * 2048;
    const unsigned short* vp = vh + ti * 2048;
    U8 kf[4], vf[4];
#pragma unroll
    for (int dd = 0; dd < 4; ++dd) kf[dd].s = *(const u16x8*)(kp + dd * 512);
#pragma unroll
    for (int r = 0; r < 4; ++r) vf[r].s = *(const u16x8*)(vp + r * 512);

    // ---- S^T = K * Q^T (32 kv x 32 q) ----
    __builtin_amdgcn_s_setprio(1);
    f32x16 s0 = {};
#pragma unroll
    for (int dd = 0; dd < 4; ++dd) s0 = MFMA32(kf[dd].b, qf[dd].b, s0);
    __builtin_amdgcn_s_setprio(0);

    // ---- causal mask (diagonal tile only): kv = kvr + 4*hi, q = lq ----
    if (ti == qb) {
      const int thr0 = lq - 4 * hi;
#pragma unroll
      for (int e = 0; e < 16; ++e) {
        const int kvr = (e & 3) + 8 * (e >> 2);
        if (kvr > thr0) s0[e] = -3e38f;
      }
    }

    // ---- scale-free softmax: P' = 2^s via raw v_exp_f32 ----
#pragma unroll
    for (int e = 0; e < 16; ++e) s0[e] = fexp2(s0[e]);

    // ---- P^T pack + cross-half redistribute (shfl) + PV + ones-rowsum ----
#define DO_SLAB(KS)                                                              \
  do {                                                                           \
    const unsigned int ua = pk2(s0[8 * (KS) + 0], s0[8 * (KS) + 1]);             \
    const unsigned int ub = pk2(s0[8 * (KS) + 2], s0[8 * (KS) + 3]);             \
    const unsigned int uc = pk2(s0[8 * (KS) + 4], s0[8 * (KS) + 5]);             \
    const unsigned int ud = pk2(s0[8 * (KS) + 6], s0[8 * (KS) + 7]);             \
    const unsigned int sa = (unsigned int)__shfl_xor((int)ua, 32);               \
    const unsigned int sb = (unsigned int)__shfl_xor((int)ub, 32);               \
    const unsigned int sc = (unsigned int)__shfl_xor((int)uc, 32);               \
    const unsigned int sd = (unsigned int)__shfl_xor((int)ud, 32);               \
    PF pf;                                                                       \
    pf.u[0] = hi ? sc : ua;                                                      \
    pf.u[1] = hi ? sd : ub;                                                      \
    pf.u[2] = hi ? uc : sa;                                                      \
    pf.u[3] = hi ? ud : sb;                                                      \
    __builtin_amdgcn_s_setprio(1);                                               \
    o0 = MFMA32(vf[2 * (KS)].b, pf.b, o0);                                       \
    o1 = MFMA32(vf[2 * (KS) + 1].b, pf.b, o1);                                   \
    osum = MFMA32(onesf.b, pf.b, osum);                                          \
    __builtin_amdgcn_s_setprio(0);                                               \
  } while (0)

    DO_SLAB(0);
    DO_SLAB(1);
#undef DO_SLAB
  }

  // ---- write per-wave partials (bf16) ----
#pragma unroll
  for (int e = 0; e < 16; ++e) {
    const int d = (e & 3) + 8 * (e >> 2) + 4 * hi;
    oLb[w][d][lq] = f2bf(o0[e]);
    oLb[w][d + 32][lq] = f2bf(o1[e]);
  }
  if (hi == 0) sumL[w][lq] = osum[0];
  __syncthreads();

  // ---- merge: plain sums (scale-free -> no factors) ----
  const int q = t >> 3, dblk = t & 7;
  const float den = sumL[0][q] + sumL[1][q] + sumL[2][q] + sumL[3][q];
  const float invd = 1.0f / den;
  u16x8 yv;
#pragma unroll
  for (int i = 0; i < 8; ++i) {
    const int d = dblk * 8 + i;
    const float a = bf2f(oLb[0][d][q]) + bf2f(oLb[1][d][q]) +
                    bf2f(oLb[2][d][q]) + bf2f(oLb[3][d][q]);
    yv[i] = f2bf(a * invd);
  }
  *(u16x8*)(Y + (size_t)(q0 + q) * 1024 + h * 64 + dblk * 8) = yv;
}

// --------------------------- launcher --------------------------------------
extern "C" void kernel_launch(void* const* d_in, const int* in_sizes, int n_in,
                              void* d_out, int out_size, void* d_ws, size_t ws_size,
                              hipStream_t stream) {
  const float* x   = (const float*)d_in[0];
  const float* ve  = (const float*)d_in[1];
  const float* qw  = (const float*)d_in[2];
  const float* lam = (const float*)d_in[3];
  const float* pw  = (const float*)d_in[4];
  float* out = (float*)d_out;

  unsigned short* ws = (unsigned short*)d_ws;
  unsigned short* x_bf  = ws;                                // 4096*1024
  unsigned short* wqkv  = x_bf + (size_t)4096 * 1024;        // 3072*1024
  unsigned short* wproj = wqkv + (size_t)3072 * 1024;        // 1024*1024
  unsigned short* qkv   = wproj + (size_t)1024 * 1024;       // 4096*3072
  unsigned short* Qb    = qkv + (size_t)4096 * 3072;         // 16*128*2048
  unsigned short* Kb    = Qb + (size_t)4096 * 1024;
  unsigned short* Vb    = Kb + (size_t)4096 * 1024;
  unsigned short* Yb    = Vb + (size_t)4096 * 1024;
  float* ct = (float*)(Yb + (size_t)4096 * 1024);            // 4096*32
  float* st = ct + 4096 * 32;

  prep<<<4608, 256, 0, stream>>>(x, qw, pw, ct, st, ws);
  gemm_bt<1><<<768, 256, 0, stream>>>(x_bf, wqkv, (void*)qkv, 4096, 3072, 1024);
  fuse_qkv<<<256, 256, 0, stream>>>(qkv, ve, lam, ct, st, Qb, Kb, Vb);
  attn_fa<<<2048, 256, 0, stream>>>(Qb, Kb, Vb, Yb);
  gemm_bt<0><<<256, 256, 0, stream>>>(Yb, wproj, (void*)out, 4096, 1024, 1024);
}

// Round 18
// 150.637 us; speedup vs baseline: 1.0428x; 1.0428x over previous
//
#include <hip/hip_runtime.h>
#include <stdint.h>

// ---------------------------------------------------------------------------
// CausalSelfAttention (T=4096, DIM=1024, 16 heads x 64) on gfx950, bf16 MFMA.
// Pipeline: prep(rope tables + casts) | GEMM1 qkv (XCD-swizzled) |
//           fuse(vmix,rms,rope -> BLOCKED Q/K + BLOCKED V^T, role-split) |
//           flash attn (swapped 32x32, split-KV x4, blocked coalesced loads,
//           scale-free softmax via raw v_exp_f32, shfl exchange, ones-MFMA
//           rowsum, DESCENDING qb = LPT schedule) | GEMM2 -> fp32
//
// r16/r17 lessons: descending-qb IS the optimal schedule (LPT: longest
// first, 1-unit blocks drain last; co-resident same-qb blocks share K/V in
// L2). Pair-balancing (halved grid) and interleaving both regressed. FROZEN.
// Scale-free softmax: O = sum(P V)/sum(P) invariant to uniform P-scale;
// P' = exp2(s) raw v_exp_f32 (s <= 11.2 by RMS-norm bound; no denormals).
// r14: no reg-prefetch rotation (scratch spills). r10: never raise min-waves
// launch bound. BANNED: v_permlane32_swap (r8/r12).
// ---------------------------------------------------------------------------

typedef __attribute__((ext_vector_type(8))) __bf16 bf16x8;
typedef __attribute__((ext_vector_type(8))) unsigned short u16x8;
typedef __attribute__((ext_vector_type(4))) float f32x4;
typedef __attribute__((ext_vector_type(16))) float f32x16;

union U8 { u16x8 s; bf16x8 b; };
union PF { unsigned int u[4]; u16x8 s; bf16x8 b; };

__device__ __forceinline__ float bf2f(unsigned short u) {
  union { unsigned int i; float f; } c; c.i = ((unsigned int)u) << 16; return c.f;
}
__device__ __forceinline__ unsigned short f2bf(float f) {
  union { __bf16 h; unsigned short u; } c; c.h = (__bf16)f; return c.u;
}
__device__ __forceinline__ unsigned int pk2(float lo, float hi) {
  return (unsigned int)f2bf(lo) | ((unsigned int)f2bf(hi) << 16);
}
__device__ __forceinline__ float fexp2(float x) {  // raw HW exp2, 1 inst
  float r;
  asm("v_exp_f32 %0, %1" : "=v"(r) : "v"(x));
  return r;
}

// async global->LDS, 16B per lane (GEMM staging only)
#define GLOAD16(gp, lp)                                                         \
  __builtin_amdgcn_global_load_lds(                                             \
      (const __attribute__((address_space(1))) void*)(gp),                      \
      (__attribute__((address_space(3))) void*)(lp), 16, 0, 0)

#define MFMA16(a, b, c) __builtin_amdgcn_mfma_f32_16x16x32_bf16((a), (b), (c), 0, 0, 0)
#define MFMA32(a, b, c) __builtin_amdgcn_mfma_f32_32x32x16_bf16((a), (b), (c), 0, 0, 0)

constexpr float ATTN_SCALE = 0.12f;
constexpr float LOG2E = 1.44269504088896340736f;
constexpr float QSCALE = ATTN_SCALE * LOG2E;  // folded into Q at fuse stage

// --------------------------- prep: rope tables + f32->bf16 casts ------------
__global__ __launch_bounds__(256) void prep(
    const float* __restrict__ x, const float* __restrict__ qw,
    const float* __restrict__ pw, float* __restrict__ ct, float* __restrict__ st,
    unsigned short* __restrict__ wsbf) {
  const int b = (int)blockIdx.x;
  if (b < 512) {
    const int i = b * 256 + threadIdx.x;
    const int tt = i >> 5, k = i & 31;
    float cv = 1.0f, sv = 0.0f;
    if (k < 16) {
      const float af = powf(1.0f / 1024.0f, (float)k * (1.0f / 15.0f));
      const float th = (float)tt * af;
      cv = cosf(th);
      sv = sinf(th);
    }
    ct[i] = cv; st[i] = sv;
    return;
  }
  const int i8 = (b - 512) * 256 + threadIdx.x;
  const float* src;
  if (i8 < 524288) src = x + (size_t)i8 * 8;
  else if (i8 < 917504) src = qw + (size_t)(i8 - 524288) * 8;
  else src = pw + (size_t)(i8 - 917504) * 8;
  const float4 a = ((const float4*)src)[0];
  const float4 c = ((const float4*)src)[1];
  u16x8 o;
  o[0] = f2bf(a.x); o[1] = f2bf(a.y); o[2] = f2bf(a.z); o[3] = f2bf(a.w);
  o[4] = f2bf(c.x); o[5] = f2bf(c.y); o[6] = f2bf(c.z); o[7] = f2bf(c.w);
  ((u16x8*)wsbf)[i8] = o;
}

// --------------------------- GEMM: C[M][N] = A[M][K] * B[N][K]^T -----------
template <int OUT_BF16>
__global__ __launch_bounds__(256) void gemm_bt(
    const unsigned short* __restrict__ A, const unsigned short* __restrict__ B,
    void* __restrict__ Cout, int M, int N, int K) {
  __shared__ unsigned short lA[128 * 32];
  __shared__ unsigned short lB[128 * 32];
  const int nbn = N >> 7;
  const int cpx = (int)gridDim.x >> 3;
  const int bid = (int)blockIdx.x;
  const int sb = (bid & 7) * cpx + (bid >> 3);  // same-XCD blocks contiguous
  const int bm = sb / nbn, bn = sb % nbn;
  const int t = threadIdx.x;
  const int w = t >> 6, l = t & 63;
  const int g = l >> 4, c = l & 15;
  const int wr = (w >> 1) * 64, wc = (w & 1) * 64;

  const int srow = t >> 2;
  const int scol = ((t & 3) << 4) ^ ((srow & 3) << 4);  // byte col, XOR swizzle
  const char* ga = (const char*)(A + (size_t)(bm * 128 + srow) * K) + scol;
  const char* gb = (const char*)(B + (size_t)(bn * 128 + srow) * K) + scol;
  const size_t rowK2 = (size_t)64 * K * 2;
  char* la_dst = (char*)lA + t * 16;
  char* lb_dst = (char*)lB + t * 16;

  f32x4 acc[4][4] = {};

  for (int kt = 0; kt < K; kt += 32) {
    const char* gak = ga + (size_t)kt * 2;
    const char* gbk = gb + (size_t)kt * 2;
    GLOAD16(gak, la_dst);
    GLOAD16(gak + rowK2, la_dst + 4096);
    GLOAD16(gbk, lb_dst);
    GLOAD16(gbk + rowK2, lb_dst + 4096);
    __syncthreads();
    U8 af[4], bfr[4];
#pragma unroll
    for (int mi = 0; mi < 4; ++mi) {
      const int row = wr + 16 * mi + c;
      af[mi].s = *(const u16x8*)((const char*)lA + row * 64 + ((16 * g) ^ ((row & 3) << 4)));
    }
#pragma unroll
    for (int ni = 0; ni < 4; ++ni) {
      const int row = wc + 16 * ni + c;
      bfr[ni].s = *(const u16x8*)((const char*)lB + row * 64 + ((16 * g) ^ ((row & 3) << 4)));
    }
#pragma unroll
    for (int mi = 0; mi < 4; ++mi)
#pragma unroll
      for (int ni = 0; ni < 4; ++ni)
        acc[mi][ni] = MFMA16(af[mi].b, bfr[ni].b, acc[mi][ni]);
    __syncthreads();
  }
#pragma unroll
  for (int mi = 0; mi < 4; ++mi) {
#pragma unroll
    for (int ni = 0; ni < 4; ++ni) {
#pragma unroll
      for (int r = 0; r < 4; ++r) {
        const int row = bm * 128 + wr + 16 * mi + 4 * g + r;
        const int col = bn * 128 + wc + 16 * ni + c;
        const float v = acc[mi][ni][r];
        if (OUT_BF16)
          ((unsigned short*)Cout)[(size_t)row * N + col] = f2bf(v);
        else
          ((float*)Cout)[(size_t)row * N + col] = v;
      }
    }
  }
}

// --------------------------- fuse: vmix + rmsnorm + rope -> blocked --------
__device__ __forceinline__ void load64f(const unsigned short* p, float* x) {
#pragma unroll
  for (int j = 0; j < 8; ++j) {
    const u16x8 v = *(const u16x8*)(p + 8 * j);
#pragma unroll
    for (int e = 0; e < 8; ++e) x[8 * j + e] = bf2f(v[e]);
  }
}

__device__ __forceinline__ void rmsrope_store_blk(const float* x, const float* ct,
                                                  const float* st, unsigned short* outp,
                                                  float pscale) {
  float ms = 0.f;
#pragma unroll
  for (int j = 0; j < 64; ++j) ms += x[j] * x[j];
  const float sc = rsqrtf(ms * (1.0f / 64.0f) + 1.1920928955078125e-7f) * pscale;
  float y[64];
#pragma unroll
  for (int j = 0; j < 32; ++j) {
    const float cc = ct[j], ss = st[j];
    const float a = x[j] * sc, b = x[j + 32] * sc;
    y[j] = a * cc + b * ss;
    y[j + 32] = b * cc - a * ss;
  }
#pragma unroll
  for (int j = 0; j < 8; ++j) {
    u16x8 o;
#pragma unroll
    for (int e = 0; e < 8; ++e) o[e] = f2bf(y[8 * j + e]);
    *(u16x8*)(outp + 256 * j) = o;
  }
}

// Role-split: 768 blocks; role = b/256 handles Q (0), K (1), or V (2) for
// tile-group bb = b%256 -> 3x wave parallelism on this latency-bound kernel.
__global__ __launch_bounds__(256) void fuse_qkv(
    const unsigned short* __restrict__ qkv,  // [4096][3072] bf16
    const float* __restrict__ ve,            // [4096][1024]
    const float* __restrict__ lam,           // [2]
    const float* __restrict__ ct, const float* __restrict__ st,  // [4096][32]
    unsigned short* __restrict__ Qb,  // blocked [16][128 tiles][2048]
    unsigned short* __restrict__ Kb,  // blocked
    unsigned short* __restrict__ Vb)  // blocked V^T
{
  __shared__ unsigned short vtile[8][32][65];  // [group][kv][d], +1 pad
  const int b = (int)blockIdx.x;  // 768 blocks
  const int role = b >> 8;        // 0=Q, 1=K, 2=V
  const int bb = b & 255;
  const int h = bb & 15, tg = bb >> 4;
  const int t = threadIdx.x;
  const int g = t >> 5, lq = t & 31;
  const int ti = tg * 8 + g;       // 32-row tile 0..127
  const int tt = ti * 32 + lq;

  const unsigned short* base = qkv + (size_t)tt * 3072 + h * 64;
  const size_t blk = (size_t)h * 262144 + (size_t)ti * 2048 + lq * 8;

  float x[64];
  if (role == 0) {
    load64f(base, x);
    rmsrope_store_blk(x, ct + tt * 32, st + tt * 32, Qb + blk, QSCALE);
    return;
  }
  if (role == 1) {
    load64f(base + 1024, x);
    rmsrope_store_blk(x, ct + tt * 32, st + tt * 32, Kb + blk, 1.0f);
    return;
  }
  // role 2: v mix -> LDS transpose tile -> blocked V^T
  const float l0 = lam[0], l1 = lam[1];
  const float* vp = ve + (size_t)tt * 1024 + h * 64;
  load64f(base + 2048, x);
#pragma unroll
  for (int j = 0; j < 64; ++j) vtile[g][lq][j] = f2bf(l0 * x[j] + l1 * vp[j]);
  __syncthreads();

  unsigned short* vo = Vb + (size_t)h * 262144 + (size_t)ti * 2048 + lq * 8;
#pragma unroll
  for (int r = 0; r < 4; ++r) {
    const int d = lq + 32 * (r & 1);
#pragma unroll
    for (int hi = 0; hi < 2; ++hi) {
      u16x8 o;
#pragma unroll
      for (int j = 0; j < 8; ++j) o[j] = vtile[g][16 * (r >> 1) + 8 * hi + j][d];
      *(u16x8*)(vo + r * 512 + hi * 256) = o;
    }
  }
}

// --------------------------- flash attention -------------------------------
// 2048 blocks (8/CU resident): block = (head, q-tile), DESCENDING qb (LPT:
// longest first, trivial drain tail, same-qb co-residency for K/V L2 reuse).
// 4 waves; split-KV: wave w owns kv-tiles ti = w, w+4, ...; private
// (osum, O^T), merged by plain sum. Loads issued-and-consumed in-iteration.
// Scale-free softmax (raw v_exp_f32). shfl_xor cross-half exchange.
// Row-sum on MFMA pipe. bf16 merge, 16.9KB LDS, launch_bounds(256,4).
__global__ __launch_bounds__(256, 4) void attn_fa(
    const unsigned short* __restrict__ Qb,  // blocked (scaled)
    const unsigned short* __restrict__ Kb,  // blocked
    const unsigned short* __restrict__ Vb,  // blocked V^T
    unsigned short* __restrict__ Y)         // [4096][1024]
{
  __shared__ unsigned short oLb[4][64][32];  // per-wave partial O^T (bf16)
  __shared__ float sumL[4][32];              // per-wave row sums

  const int b = (int)blockIdx.x;
  const int h = 2 * (b & 7) + ((b >> 3) & 1);  // same-h -> same XCD (b%8)
  const int qb = 127 - (b >> 4);               // LPT: longest first
  const int q0 = qb * 32;
  const int t = threadIdx.x;
  const int w = t >> 6, l = t & 63;
  const int lq = l & 31;    // this lane's q row
  const int hi = l >> 5;    // k/kv half selector

  const unsigned short* kh = Kb + (size_t)h * 262144 + l * 8;
  const unsigned short* vh = Vb + (size_t)h * 262144 + l * 8;

  // Q fragments: blocked tile qb
  U8 qf[4];
  {
    const unsigned short* qp = Qb + (size_t)h * 262144 + qb * 2048 + l * 8;
#pragma unroll
    for (int dd = 0; dd < 4; ++dd) qf[dd].s = *(const u16x8*)(qp + dd * 512);
  }

  U8 onesf;
#pragma unroll
  for (int e = 0; e < 8; ++e) onesf.s[e] = 0x3F80;  // bf16 1.0

  f32x16 o0 = {}, o1 = {};   // O^T: d rows 0-31 / 32-63, col q = lq
  f32x16 osum = {};          // row-sum accum on MFMA pipe (read [0])

  for (int ti = w; ti <= qb; ti += 4) {
    const unsigned short* kp = kh + ti * 2048;
    const unsigned short* vp = vh + ti * 2048;
    U8 kf[4], vf[4];
#pragma unroll
    for (int dd = 0; dd < 4; ++dd) kf[dd].s = *(const u16x8*)(kp + dd * 512);
#pragma unroll
    for (int r = 0; r < 4; ++r) vf[r].s = *(const u16x8*)(vp + r * 512);

    // ---- S^T = K * Q^T (32 kv x 32 q) ----
    __builtin_amdgcn_s_setprio(1);
    f32x16 s0 = {};
#pragma unroll
    for (int dd = 0; dd < 4; ++dd) s0 = MFMA32(kf[dd].b, qf[dd].b, s0);
    __builtin_amdgcn_s_setprio(0);

    // ---- causal mask (diagonal tile only): kv = kvr + 4*hi, q = lq ----
    if (ti == qb) {
      const int thr0 = lq - 4 * hi;
#pragma unroll
      for (int e = 0; e < 16; ++e) {
        const int kvr = (e & 3) + 8 * (e >> 2);
        if (kvr > thr0) s0[e] = -3e38f;
      }
    }

    // ---- scale-free softmax: P' = 2^s via raw v_exp_f32 ----
#pragma unroll
    for (int e = 0; e < 16; ++e) s0[e] = fexp2(s0[e]);

    // ---- P^T pack + cross-half redistribute (shfl) + PV + ones-rowsum ----
#define DO_SLAB(KS)                                                              \
  do {                                                                           \
    const unsigned int ua = pk2(s0[8 * (KS) + 0], s0[8 * (KS) + 1]);             \
    const unsigned int ub = pk2(s0[8 * (KS) + 2], s0[8 * (KS) + 3]);             \
    const unsigned int uc = pk2(s0[8 * (KS) + 4], s0[8 * (KS) + 5]);             \
    const unsigned int ud = pk2(s0[8 * (KS) + 6], s0[8 * (KS) + 7]);             \
    const unsigned int sa = (unsigned int)__shfl_xor((int)ua, 32);               \
    const unsigned int sb = (unsigned int)__shfl_xor((int)ub, 32);               \
    const unsigned int sc = (unsigned int)__shfl_xor((int)uc, 32);               \
    const unsigned int sd = (unsigned int)__shfl_xor((int)ud, 32);               \
    PF pf;                                                                       \
    pf.u[0] = hi ? sc : ua;                                                      \
    pf.u[1] = hi ? sd : ub;                                                      \
    pf.u[2] = hi ? uc : sa;                                                      \
    pf.u[3] = hi ? ud : sb;                                                      \
    __builtin_amdgcn_s_setprio(1);                                               \
    o0 = MFMA32(vf[2 * (KS)].b, pf.b, o0);                                       \
    o1 = MFMA32(vf[2 * (KS) + 1].b, pf.b, o1);                                   \
    osum = MFMA32(onesf.b, pf.b, osum);                                          \
    __builtin_amdgcn_s_setprio(0);                                               \
  } while (0)

    DO_SLAB(0);
    DO_SLAB(1);
#undef DO_SLAB
  }

  // ---- write per-wave partials (bf16) ----
#pragma unroll
  for (int e = 0; e < 16; ++e) {
    const int d = (e & 3) + 8 * (e >> 2) + 4 * hi;
    oLb[w][d][lq] = f2bf(o0[e]);
    oLb[w][d + 32][lq] = f2bf(o1[e]);
  }
  if (hi == 0) sumL[w][lq] = osum[0];
  __syncthreads();

  // ---- merge: plain sums (scale-free -> no factors) ----
  const int q = t >> 3, dblk = t & 7;
  const float den = sumL[0][q] + sumL[1][q] + sumL[2][q] + sumL[3][q];
  const float invd = 1.0f / den;
  u16x8 yv;
#pragma unroll
  for (int i = 0; i < 8; ++i) {
    const int d = dblk * 8 + i;
    const float a = bf2f(oLb[0][d][q]) + bf2f(oLb[1][d][q]) +
                    bf2f(oLb[2][d][q]) + bf2f(oLb[3][d][q]);
    yv[i] = f2bf(a * invd);
  }
  *(u16x8*)(Y + (size_t)(q0 + q) * 1024 + h * 64 + dblk * 8) = yv;
}

// --------------------------- launcher --------------------------------------
extern "C" void kernel_launch(void* const* d_in, const int* in_sizes, int n_in,
                              void* d_out, int out_size, void* d_ws, size_t ws_size,
                              hipStream_t stream) {
  const float* x   = (const float*)d_in[0];
  const float* ve  = (const float*)d_in[1];
  const float* qw  = (const float*)d_in[2];
  const float* lam = (const float*)d_in[3];
  const float* pw  = (const float*)d_in[4];
  float* out = (float*)d_out;

  unsigned short* ws = (unsigned short*)d_ws;
  unsigned short* x_bf  = ws;                                // 4096*1024
  unsigned short* wqkv  = x_bf + (size_t)4096 * 1024;        // 3072*1024
  unsigned short* wproj = wqkv + (size_t)3072 * 1024;        // 1024*1024
  unsigned short* qkv   = wproj + (size_t)1024 * 1024;       // 4096*3072
  unsigned short* Qb    = qkv + (size_t)4096 * 3072;         // 16*128*2048
  unsigned short* Kb    = Qb + (size_t)4096 * 1024;
  unsigned short* Vb    = Kb + (size_t)4096 * 1024;
  unsigned short* Yb    = Vb + (size_t)4096 * 1024;
  float* ct = (float*)(Yb + (size_t)4096 * 1024);            // 4096*32
  float* st = ct + 4096 * 32;

  prep<<<4608, 256, 0, stream>>>(x, qw, pw, ct, st, ws);
  gemm_bt<1><<<768, 256, 0, stream>>>(x_bf, wqkv, (void*)qkv, 4096, 3072, 1024);
  fuse_qkv<<<768, 256, 0, stream>>>(qkv, ve, lam, ct, st, Qb, Kb, Vb);
  attn_fa<<<2048, 256, 0, stream>>>(Qb, Kb, Vb, Yb);
  gemm_bt<0><<<256, 256, 0, stream>>>(Yb, wproj, (void*)out, 4096, 1024, 1024);
}

// Round 19
// 144.460 us; speedup vs baseline: 1.0874x; 1.0428x over previous
//
#include <hip/hip_runtime.h>
#include <stdint.h>

// ---------------------------------------------------------------------------
// CausalSelfAttention (T=4096, DIM=1024, 16 heads x 64) on gfx950, bf16 MFMA.
// Pipeline: prep(rope tables + casts) | GEMM1 qkv (XCD-swizzled, 128^2) |
//           fuse(vmix,rms,rope -> BLOCKED Q/K + BLOCKED V^T) | flash attn
//           (swapped 32x32, split-KV x4, blocked coalesced loads, scale-free
//           softmax via raw v_exp_f32, shfl exchange, ones-MFMA rowsum,
//           DESCENDING qb = LPT) | GEMM2 via 64x128-tile kernel (512 blocks
//           = 2/CU; the 128^2 grid was 256 blocks = 1/CU, latency-exposed)
//
// r16/r17: descending-qb IS optimal (LPT + same-qb L2 sharing). FROZEN.
// r18: fuse role-split neutral -> reverted. Scale-free softmax: P'=exp2(s),
// no max subtract (s <= 11.2 by RMS-norm bound); raw v_exp_f32 (1 inst).
// r14: no reg-prefetch rotation (spills). r10: never raise min-waves bound.
// BANNED: v_permlane32_swap (r8/r12).
// ---------------------------------------------------------------------------

typedef __attribute__((ext_vector_type(8))) __bf16 bf16x8;
typedef __attribute__((ext_vector_type(8))) unsigned short u16x8;
typedef __attribute__((ext_vector_type(4))) float f32x4;
typedef __attribute__((ext_vector_type(16))) float f32x16;

union U8 { u16x8 s; bf16x8 b; };
union PF { unsigned int u[4]; u16x8 s; bf16x8 b; };

__device__ __forceinline__ float bf2f(unsigned short u) {
  union { unsigned int i; float f; } c; c.i = ((unsigned int)u) << 16; return c.f;
}
__device__ __forceinline__ unsigned short f2bf(float f) {
  union { __bf16 h; unsigned short u; } c; c.h = (__bf16)f; return c.u;
}
__device__ __forceinline__ unsigned int pk2(float lo, float hi) {
  return (unsigned int)f2bf(lo) | ((unsigned int)f2bf(hi) << 16);
}
__device__ __forceinline__ float fexp2(float x) {  // raw HW exp2, 1 inst
  float r;
  asm("v_exp_f32 %0, %1" : "=v"(r) : "v"(x));
  return r;
}

// async global->LDS, 16B per lane (GEMM staging only)
#define GLOAD16(gp, lp)                                                         \
  __builtin_amdgcn_global_load_lds(                                             \
      (const __attribute__((address_space(1))) void*)(gp),                      \
      (__attribute__((address_space(3))) void*)(lp), 16, 0, 0)

#define MFMA16(a, b, c) __builtin_amdgcn_mfma_f32_16x16x32_bf16((a), (b), (c), 0, 0, 0)
#define MFMA32(a, b, c) __builtin_amdgcn_mfma_f32_32x32x16_bf16((a), (b), (c), 0, 0, 0)

constexpr float ATTN_SCALE = 0.12f;
constexpr float LOG2E = 1.44269504088896340736f;
constexpr float QSCALE = ATTN_SCALE * LOG2E;  // folded into Q at fuse stage

// --------------------------- prep: rope tables + f32->bf16 casts ------------
__global__ __launch_bounds__(256) void prep(
    const float* __restrict__ x, const float* __restrict__ qw,
    const float* __restrict__ pw, float* __restrict__ ct, float* __restrict__ st,
    unsigned short* __restrict__ wsbf) {
  const int b = (int)blockIdx.x;
  if (b < 512) {
    const int i = b * 256 + threadIdx.x;
    const int tt = i >> 5, k = i & 31;
    float cv = 1.0f, sv = 0.0f;
    if (k < 16) {
      const float af = powf(1.0f / 1024.0f, (float)k * (1.0f / 15.0f));
      const float th = (float)tt * af;
      cv = cosf(th);
      sv = sinf(th);
    }
    ct[i] = cv; st[i] = sv;
    return;
  }
  const int i8 = (b - 512) * 256 + threadIdx.x;
  const float* src;
  if (i8 < 524288) src = x + (size_t)i8 * 8;
  else if (i8 < 917504) src = qw + (size_t)(i8 - 524288) * 8;
  else src = pw + (size_t)(i8 - 917504) * 8;
  const float4 a = ((const float4*)src)[0];
  const float4 c = ((const float4*)src)[1];
  u16x8 o;
  o[0] = f2bf(a.x); o[1] = f2bf(a.y); o[2] = f2bf(a.z); o[3] = f2bf(a.w);
  o[4] = f2bf(c.x); o[5] = f2bf(c.y); o[6] = f2bf(c.z); o[7] = f2bf(c.w);
  ((u16x8*)wsbf)[i8] = o;
}

// --------------------------- GEMM 128^2: C = A * B^T -----------------------
template <int OUT_BF16>
__global__ __launch_bounds__(256) void gemm_bt(
    const unsigned short* __restrict__ A, const unsigned short* __restrict__ B,
    void* __restrict__ Cout, int M, int N, int K) {
  __shared__ unsigned short lA[128 * 32];
  __shared__ unsigned short lB[128 * 32];
  const int nbn = N >> 7;
  const int cpx = (int)gridDim.x >> 3;
  const int bid = (int)blockIdx.x;
  const int sb = (bid & 7) * cpx + (bid >> 3);  // same-XCD blocks contiguous
  const int bm = sb / nbn, bn = sb % nbn;
  const int t = threadIdx.x;
  const int w = t >> 6, l = t & 63;
  const int g = l >> 4, c = l & 15;
  const int wr = (w >> 1) * 64, wc = (w & 1) * 64;

  const int srow = t >> 2;
  const int scol = ((t & 3) << 4) ^ ((srow & 3) << 4);  // byte col, XOR swizzle
  const char* ga = (const char*)(A + (size_t)(bm * 128 + srow) * K) + scol;
  const char* gb = (const char*)(B + (size_t)(bn * 128 + srow) * K) + scol;
  const size_t rowK2 = (size_t)64 * K * 2;
  char* la_dst = (char*)lA + t * 16;
  char* lb_dst = (char*)lB + t * 16;

  f32x4 acc[4][4] = {};

  for (int kt = 0; kt < K; kt += 32) {
    const char* gak = ga + (size_t)kt * 2;
    const char* gbk = gb + (size_t)kt * 2;
    GLOAD16(gak, la_dst);
    GLOAD16(gak + rowK2, la_dst + 4096);
    GLOAD16(gbk, lb_dst);
    GLOAD16(gbk + rowK2, lb_dst + 4096);
    __syncthreads();
    U8 af[4], bfr[4];
#pragma unroll
    for (int mi = 0; mi < 4; ++mi) {
      const int row = wr + 16 * mi + c;
      af[mi].s = *(const u16x8*)((const char*)lA + row * 64 + ((16 * g) ^ ((row & 3) << 4)));
    }
#pragma unroll
    for (int ni = 0; ni < 4; ++ni) {
      const int row = wc + 16 * ni + c;
      bfr[ni].s = *(const u16x8*)((const char*)lB + row * 64 + ((16 * g) ^ ((row & 3) << 4)));
    }
#pragma unroll
    for (int mi = 0; mi < 4; ++mi)
#pragma unroll
      for (int ni = 0; ni < 4; ++ni)
        acc[mi][ni] = MFMA16(af[mi].b, bfr[ni].b, acc[mi][ni]);
    __syncthreads();
  }
#pragma unroll
  for (int mi = 0; mi < 4; ++mi) {
#pragma unroll
    for (int ni = 0; ni < 4; ++ni) {
#pragma unroll
      for (int r = 0; r < 4; ++r) {
        const int row = bm * 128 + wr + 16 * mi + 4 * g + r;
        const int col = bn * 128 + wc + 16 * ni + c;
        const float v = acc[mi][ni][r];
        if (OUT_BF16)
          ((unsigned short*)Cout)[(size_t)row * N + col] = f2bf(v);
        else
          ((float*)Cout)[(size_t)row * N + col] = v;
      }
    }
  }
}

// --------------------------- GEMM 64x128: C = A * B^T (fp32 out) -----------
// For the small-grid GEMM2: BM=64 -> 512 blocks (2/CU co-resident). 4 waves
// split N: wave w computes rows 0..63 x cols w*32..+32 (acc[4][2]).
__global__ __launch_bounds__(256) void gemm_bt64(
    const unsigned short* __restrict__ A, const unsigned short* __restrict__ B,
    float* __restrict__ Cout, int M, int N, int K) {
  __shared__ unsigned short lA[64 * 32];    // 4KB
  __shared__ unsigned short lB[128 * 32];   // 8KB
  const int nbn = N >> 7;
  const int cpx = (int)gridDim.x >> 3;
  const int bid = (int)blockIdx.x;
  const int sb = (bid & 7) * cpx + (bid >> 3);
  const int bm = sb / nbn, bn = sb % nbn;
  const int t = threadIdx.x;
  const int w = t >> 6, l = t & 63;
  const int g = l >> 4, c = l & 15;
  const int wc = w * 32;

  const int srow = t >> 2;                              // 0..63
  const int scol = ((t & 3) << 4) ^ ((srow & 3) << 4);  // byte col, swizzled
  const char* ga = (const char*)(A + (size_t)(bm * 64 + srow) * K) + scol;
  const char* gb = (const char*)(B + (size_t)(bn * 128 + srow) * K) + scol;
  const size_t rowK2 = (size_t)64 * K * 2;
  char* la_dst = (char*)lA + t * 16;
  char* lb_dst = (char*)lB + t * 16;

  f32x4 acc[4][2] = {};

  for (int kt = 0; kt < K; kt += 32) {
    const char* gak = ga + (size_t)kt * 2;
    const char* gbk = gb + (size_t)kt * 2;
    GLOAD16(gak, la_dst);                    // A: 64 rows = one full pass
    GLOAD16(gbk, lb_dst);                    // B rows 0..63
    GLOAD16(gbk + rowK2, lb_dst + 4096);     // B rows 64..127
    __syncthreads();
    U8 af[4], bfr[2];
#pragma unroll
    for (int mi = 0; mi < 4; ++mi) {
      const int row = 16 * mi + c;
      af[mi].s = *(const u16x8*)((const char*)lA + row * 64 + ((16 * g) ^ ((row & 3) << 4)));
    }
#pragma unroll
    for (int ni = 0; ni < 2; ++ni) {
      const int row = wc + 16 * ni + c;
      bfr[ni].s = *(const u16x8*)((const char*)lB + row * 64 + ((16 * g) ^ ((row & 3) << 4)));
    }
#pragma unroll
    for (int mi = 0; mi < 4; ++mi)
#pragma unroll
      for (int ni = 0; ni < 2; ++ni)
        acc[mi][ni] = MFMA16(af[mi].b, bfr[ni].b, acc[mi][ni]);
    __syncthreads();
  }
#pragma unroll
  for (int mi = 0; mi < 4; ++mi) {
#pragma unroll
    for (int ni = 0; ni < 2; ++ni) {
#pragma unroll
      for (int r = 0; r < 4; ++r) {
        const int row = bm * 64 + 16 * mi + 4 * g + r;
        const int col = bn * 128 + wc + 16 * ni + c;
        Cout[(size_t)row * N + col] = acc[mi][ni][r];
      }
    }
  }
}

// --------------------------- fuse: vmix + rmsnorm + rope -> blocked --------
__device__ __forceinline__ void load64f(const unsigned short* p, float* x) {
#pragma unroll
  for (int j = 0; j < 8; ++j) {
    const u16x8 v = *(const u16x8*)(p + 8 * j);
#pragma unroll
    for (int e = 0; e < 8; ++e) x[8 * j + e] = bf2f(v[e]);
  }
}

__device__ __forceinline__ void rmsrope_store_blk(const float* x, const float* ct,
                                                  const float* st, unsigned short* outp,
                                                  float pscale) {
  float ms = 0.f;
#pragma unroll
  for (int j = 0; j < 64; ++j) ms += x[j] * x[j];
  const float sc = rsqrtf(ms * (1.0f / 64.0f) + 1.1920928955078125e-7f) * pscale;
  float y[64];
#pragma unroll
  for (int j = 0; j < 32; ++j) {
    const float cc = ct[j], ss = st[j];
    const float a = x[j] * sc, b = x[j + 32] * sc;
    y[j] = a * cc + b * ss;
    y[j + 32] = b * cc - a * ss;
  }
#pragma unroll
  for (int j = 0; j < 8; ++j) {
    u16x8 o;
#pragma unroll
    for (int e = 0; e < 8; ++e) o[e] = f2bf(y[8 * j + e]);
    *(u16x8*)(outp + 256 * j) = o;
  }
}

__global__ __launch_bounds__(256) void fuse_qkv(
    const unsigned short* __restrict__ qkv,  // [4096][3072] bf16
    const float* __restrict__ ve,            // [4096][1024]
    const float* __restrict__ lam,           // [2]
    const float* __restrict__ ct, const float* __restrict__ st,  // [4096][32]
    unsigned short* __restrict__ Qb,  // blocked [16][128 tiles][2048]
    unsigned short* __restrict__ Kb,  // blocked
    unsigned short* __restrict__ Vb)  // blocked V^T
{
  __shared__ unsigned short vtile[8][32][65];  // [group][kv][d], +1 pad
  const int b = (int)blockIdx.x;  // 256 blocks
  const int h = b & 15, tg = b >> 4;
  const int t = threadIdx.x;
  const int g = t >> 5, lq = t & 31;
  const int ti = tg * 8 + g;       // 32-row tile 0..127
  const int tt = ti * 32 + lq;

  const unsigned short* base = qkv + (size_t)tt * 3072 + h * 64;
  const float* ctp = ct + tt * 32;
  const float* stp = st + tt * 32;
  const size_t blk = (size_t)h * 262144 + (size_t)ti * 2048 + lq * 8;

  float x[64];
  load64f(base, x);
  rmsrope_store_blk(x, ctp, stp, Qb + blk, QSCALE);
  load64f(base + 1024, x);
  rmsrope_store_blk(x, ctp, stp, Kb + blk, 1.0f);

  // v mix -> LDS transpose tile
  const float l0 = lam[0], l1 = lam[1];
  const float* vp = ve + (size_t)tt * 1024 + h * 64;
  load64f(base + 2048, x);
#pragma unroll
  for (int j = 0; j < 64; ++j) vtile[g][lq][j] = f2bf(l0 * x[j] + l1 * vp[j]);
  __syncthreads();

  unsigned short* vo = Vb + (size_t)h * 262144 + (size_t)ti * 2048 + lq * 8;
#pragma unroll
  for (int r = 0; r < 4; ++r) {
    const int d = lq + 32 * (r & 1);
#pragma unroll
    for (int hi = 0; hi < 2; ++hi) {
      u16x8 o;
#pragma unroll
      for (int j = 0; j < 8; ++j) o[j] = vtile[g][16 * (r >> 1) + 8 * hi + j][d];
      *(u16x8*)(vo + r * 512 + hi * 256) = o;
    }
  }
}

// --------------------------- flash attention -------------------------------
// 2048 blocks (8/CU resident): block = (head, q-tile), DESCENDING qb (LPT).
// 4 waves; split-KV: wave w owns kv-tiles ti = w, w+4, ...; private
// (osum, O^T), merged by plain sum. Loads issued-and-consumed in-iteration.
// Scale-free softmax (raw v_exp_f32). shfl_xor cross-half exchange.
// Row-sum on MFMA pipe. bf16 merge, 16.9KB LDS, launch_bounds(256,4).
__global__ __launch_bounds__(256, 4) void attn_fa(
    const unsigned short* __restrict__ Qb,  // blocked (scaled)
    const unsigned short* __restrict__ Kb,  // blocked
    const unsigned short* __restrict__ Vb,  // blocked V^T
    unsigned short* __restrict__ Y)         // [4096][1024]
{
  __shared__ unsigned short oLb[4][64][32];  // per-wave partial O^T (bf16)
  __shared__ float sumL[4][32];              // per-wave row sums

  const int b = (int)blockIdx.x;
  const int h = 2 * (b & 7) + ((b >> 3) & 1);  // same-h -> same XCD (b%8)
  const int qb = 127 - (b >> 4);               // LPT: longest first
  const int q0 = qb * 32;
  const int t = threadIdx.x;
  const int w = t >> 6, l = t & 63;
  const int lq = l & 31;    // this lane's q row
  const int hi = l >> 5;    // k/kv half selector

  const unsigned short* kh = Kb + (size_t)h * 262144 + l * 8;
  const unsigned short* vh = Vb + (size_t)h * 262144 + l * 8;

  // Q fragments: blocked tile qb
  U8 qf[4];
  {
    const unsigned short* qp = Qb + (size_t)h * 262144 + qb * 2048 + l * 8;
#pragma unroll
    for (int dd = 0; dd < 4; ++dd) qf[dd].s = *(const u16x8*)(qp + dd * 512);
  }

  U8 onesf;
#pragma unroll
  for (int e = 0; e < 8; ++e) onesf.s[e] = 0x3F80;  // bf16 1.0

  f32x16 o0 = {}, o1 = {};   // O^T: d rows 0-31 / 32-63, col q = lq
  f32x16 osum = {};          // row-sum accum on MFMA pipe (read [0])

  for (int ti = w; ti <= qb; ti += 4) {
    const unsigned short* kp = kh + ti * 2048;
    const unsigned short* vp = vh + ti * 2048;
    U8 kf[4], vf[4];
#pragma unroll
    for (int dd = 0; dd < 4; ++dd) kf[dd].s = *(const u16x8*)(kp + dd * 512);
#pragma unroll
    for (int r = 0; r < 4; ++r) vf[r].s = *(const u16x8*)(vp + r * 512);

    // ---- S^T = K * Q^T (32 kv x 32 q) ----
    __builtin_amdgcn_s_setprio(1);
    f32x16 s0 = {};
#pragma unroll
    for (int dd = 0; dd < 4; ++dd) s0 = MFMA32(kf[dd].b, qf[dd].b, s0);
    __builtin_amdgcn_s_setprio(0);

    // ---- causal mask (diagonal tile only): kv = kvr + 4*hi, q = lq ----
    if (ti == qb) {
      const int thr0 = lq - 4 * hi;
#pragma unroll
      for (int e = 0; e < 16; ++e) {
        const int kvr = (e & 3) + 8 * (e >> 2);
        if (kvr > thr0) s0[e] = -3e38f;
      }
    }

    // ---- scale-free softmax: P' = 2^s via raw v_exp_f32 ----
#pragma unroll
    for (int e = 0; e < 16; ++e) s0[e] = fexp2(s0[e]);

    // ---- P^T pack + cross-half redistribute (shfl) + PV + ones-rowsum ----
#define DO_SLAB(KS)                                                              \
  do {                                                                           \
    const unsigned int ua = pk2(s0[8 * (KS) + 0], s0[8 * (KS) + 1]);             \
    const unsigned int ub = pk2(s0[8 * (KS) + 2], s0[8 * (KS) + 3]);             \
    const unsigned int uc = pk2(s0[8 * (KS) + 4], s0[8 * (KS) + 5]);             \
    const unsigned int ud = pk2(s0[8 * (KS) + 6], s0[8 * (KS) + 7]);             \
    const unsigned int sa = (unsigned int)__shfl_xor((int)ua, 32);               \
    const unsigned int sb = (unsigned int)__shfl_xor((int)ub, 32);               \
    const unsigned int sc = (unsigned int)__shfl_xor((int)uc, 32);               \
    const unsigned int sd = (unsigned int)__shfl_xor((int)ud, 32);               \
    PF pf;                                                                       \
    pf.u[0] = hi ? sc : ua;                                                      \
    pf.u[1] = hi ? sd : ub;                                                      \
    pf.u[2] = hi ? uc : sa;                                                      \
    pf.u[3] = hi ? ud : sb;                                                      \
    __builtin_amdgcn_s_setprio(1);                                               \
    o0 = MFMA32(vf[2 * (KS)].b, pf.b, o0);                                       \
    o1 = MFMA32(vf[2 * (KS) + 1].b, pf.b, o1);                                   \
    osum = MFMA32(onesf.b, pf.b, osum);                                          \
    __builtin_amdgcn_s_setprio(0);                                               \
  } while (0)

    DO_SLAB(0);
    DO_SLAB(1);
#undef DO_SLAB
  }

  // ---- write per-wave partials (bf16) ----
#pragma unroll
  for (int e = 0; e < 16; ++e) {
    const int d = (e & 3) + 8 * (e >> 2) + 4 * hi;
    oLb[w][d][lq] = f2bf(o0[e]);
    oLb[w][d + 32][lq] = f2bf(o1[e]);
  }
  if (hi == 0) sumL[w][lq] = osum[0];
  __syncthreads();

  // ---- merge: plain sums (scale-free -> no factors) ----
  const int q = t >> 3, dblk = t & 7;
  const float den = sumL[0][q] + sumL[1][q] + sumL[2][q] + sumL[3][q];
  const float invd = 1.0f / den;
  u16x8 yv;
#pragma unroll
  for (int i = 0; i < 8; ++i) {
    const int d = dblk * 8 + i;
    const float a = bf2f(oLb[0][d][q]) + bf2f(oLb[1][d][q]) +
                    bf2f(oLb[2][d][q]) + bf2f(oLb[3][d][q]);
    yv[i] = f2bf(a * invd);
  }
  *(u16x8*)(Y + (size_t)(q0 + q) * 1024 + h * 64 + dblk * 8) = yv;
}

// --------------------------- launcher --------------------------------------
extern "C" void kernel_launch(void* const* d_in, const int* in_sizes, int n_in,
                              void* d_out, int out_size, void* d_ws, size_t ws_size,
                              hipStream_t stream) {
  const float* x   = (const float*)d_in[0];
  const float* ve  = (const float*)d_in[1];
  const float* qw  = (const float*)d_in[2];
  const float* lam = (const float*)d_in[3];
  const float* pw  = (const float*)d_in[4];
  float* out = (float*)d_out;

  unsigned short* ws = (unsigned short*)d_ws;
  unsigned short* x_bf  = ws;                                // 4096*1024
  unsigned short* wqkv  = x_bf + (size_t)4096 * 1024;        // 3072*1024
  unsigned short* wproj = wqkv + (size_t)3072 * 1024;        // 1024*1024
  unsigned short* qkv   = wproj + (size_t)1024 * 1024;       // 4096*3072
  unsigned short* Qb    = qkv + (size_t)4096 * 3072;         // 16*128*2048
  unsigned short* Kb    = Qb + (size_t)4096 * 1024;
  unsigned short* Vb    = Kb + (size_t)4096 * 1024;
  unsigned short* Yb    = Vb + (size_t)4096 * 1024;
  float* ct = (float*)(Yb + (size_t)4096 * 1024);            // 4096*32
  float* st = ct + 4096 * 32;

  prep<<<4608, 256, 0, stream>>>(x, qw, pw, ct, st, ws);
  gemm_bt<1><<<768, 256, 0, stream>>>(x_bf, wqkv, (void*)qkv, 4096, 3072, 1024);
  fuse_qkv<<<256, 256, 0, stream>>>(qkv, ve, lam, ct, st, Qb, Kb, Vb);
  attn_fa<<<2048, 256, 0, stream>>>(Qb, Kb, Vb, Yb);
  gemm_bt64<<<512, 256, 0, stream>>>(Yb, wproj, out, 4096, 1024, 1024);
}